// Round 17
// baseline (197.471 us; speedup 1.0000x reference)
//
#include <hip/hip_runtime.h>
#include <hip/hip_bf16.h>
#include <math.h>

typedef short bf16x8 __attribute__((ext_vector_type(8)));
typedef float f32x4 __attribute__((ext_vector_type(4)));

#define KDIM 768
#define NTAG 10000
#define NVOC 21128
#define HID 256
#define NTOK 4096
#define NCHUNK 24
#define CHUNK 881                 // ceil(21128/24)
#define NTILE 28                  // ceil(881/32)  (32-row tiles)
#define TILEB 24576               // bytes per packed B tile (32 rows x 768 fp8)
#define M0 4.0f                   // fixed softmax shift (logits ~N(0,0.55))
#define WMSCALE 16.0f             // Wm pre-scale (fp8 subnormal avoidance)
#define INVSCALE 0.0625f
#define LOG2E 1.44269504f

// ws layout (bytes)
#define WS_A     0ull                    // fp8  [4096][768] title          (3145728)
#define WS_PSUM  3145728ull              // f32  [4096][24]                 (393216)
#define WS_GOLD  3538944ull              // f32  [4096]                     (16384)
#define WS_TAGL  3555328ull              // f32  [1] atomic                 (64)
#define WS_WM8   3555392ull              // fp8 packed [24][28][24576]      (16515072)
#define WS_NEED  (WS_WM8 + 16515072ull + 65536ull)

#define OUT_EMB  320000
#define OUT_LTAG 328192
#define OUT_LMLM 328193

#define MLM_BLKS 768
#define TAG_BLKS 625              // 1 ntile (16 tags) per block, 24KB LDS
#define GOLD_BLKS 1024            // 4 tokens per block, 0 LDS
#define EMB_BLKS 32
#define TAIL_GRID (TAG_BLKS + GOLD_BLKS + EMB_BLKS)   // 1681
#define CONV_BLKS 1536            // title groups: 393216/256
#define WMCV_BLKS (NCHUNK*NTILE)  // 672

typedef const __attribute__((address_space(1))) unsigned int glds_g;
typedef __attribute__((address_space(3))) unsigned int glds_l;

static __device__ __forceinline__ unsigned short f2bf(float f) {
  unsigned u = __builtin_bit_cast(unsigned, f);
  u = u + 0x7FFFu + ((u >> 16) & 1u);
  return (unsigned short)(u >> 16);
}

// pack 4 floats -> 4 fp8 e4m3 bytes
static __device__ __forceinline__ int pk4_fp8(float4 v, float scale) {
  int w = __builtin_amdgcn_cvt_pk_fp8_f32(v.x * scale, v.y * scale, 0, false);
  w = __builtin_amdgcn_cvt_pk_fp8_f32(v.z * scale, v.w * scale, w, true);
  return w;
}

static __device__ __forceinline__ bf16x8 cvt8(float4 f0, float4 f1) {
  bf16x8 o;
  o[0] = (short)f2bf(f0.x); o[1] = (short)f2bf(f0.y);
  o[2] = (short)f2bf(f0.z); o[3] = (short)f2bf(f0.w);
  o[4] = (short)f2bf(f1.x); o[5] = (short)f2bf(f1.y);
  o[6] = (short)f2bf(f1.z); o[7] = (short)f2bf(f1.w);
  return o;
}

// ---------------- conversions: title->fp8 | Wm->packed fp8 tiles ----------------
// Packed tile image (32 rows x 768) for 16x16x32: piece (row r, k-octet q=kk*4+g)
// at byte kk*1024 + g*256 + r*8.
__global__ __launch_bounds__(256) void k_conv(
    const float* __restrict__ title, const float* __restrict__ Wm,
    char* __restrict__ A8, char* __restrict__ Wm8) {
  __shared__ __align__(1024) char tsm[TILEB];
  const int bid = blockIdx.x, tid = threadIdx.x;
  if (bid < CONV_BLKS) {
    int i = bid * 256 + tid;
    float4 v0 = ((const float4*)title)[i * 2];
    float4 v1 = ((const float4*)title)[i * 2 + 1];
    int2 o = {pk4_fp8(v0, 1.f), pk4_fp8(v1, 1.f)};
    *(int2*)(A8 + (size_t)i * 8) = o;
  } else {
    const int wblk = bid - CONV_BLKS;
    const int chunk = wblk / NTILE, tile = wblk % NTILE;
    const int n0 = chunk * CHUNK + tile * 32;
    const int nend = min(chunk * CHUNK + CHUNK, NVOC);
    #pragma unroll
    for (int j = 0; j < 12; ++j) {
      int p = j * 256 + tid;            // 0..3071
      int r = p / 96, q = p % 96;       // row, k-octet
      int n = n0 + r;
      int2 o = {0, 0};
      if (n < nend) {
        const float* wp = Wm + (size_t)n * KDIM + q * 8;
        o.x = pk4_fp8(((const float4*)wp)[0], WMSCALE);
        o.y = pk4_fp8(((const float4*)wp)[1], WMSCALE);
      }
      *(int2*)(tsm + (q >> 2) * 1024 + (q & 3) * 256 + r * 8) = o;
    }
    __syncthreads();
    char* dst = Wm8 + (size_t)wblk * TILEB;
    #pragma unroll
    for (int j = 0; j < 6; ++j) {
      int idx = j * 256 + tid;
      *(int4*)(dst + idx * 16) = *(const int4*)(tsm + idx * 16);
    }
  }
}

// ---------------- MLM GEMM (fp8) + streaming sum-exp (pure, grid 768) --------
// chunk = bid%24 (XCD c%8), mt = bid/24. 4 waves x 32 rows x 32-col tiles.
// LDS B tile 24KB packed image; lane (g,col) b64-reads at col*8+g*256+kk*1024
// (+128 second N-half) -> conflict-free. 2-buffer, vmcnt(6), 2 barriers/tile.
template<bool WM8>
__global__ __launch_bounds__(256)
__attribute__((amdgpu_waves_per_eu(3, 3)))
void k_mlm(
    const char* __restrict__ A8,
    const float* __restrict__ Wm,
    const char* __restrict__ Wm8,
    const float* __restrict__ bm,
    float* __restrict__ psum) {
  __shared__ __align__(1024) char smem[2 * TILEB + 3584];   // 52736 B
  char (*Bsm)[TILEB] = (char(*)[TILEB])smem;
  float* biasS = (float*)(smem + 2 * TILEB);                // [NTILE*32]
  const int tid = threadIdx.x;
  const int wave = tid >> 6, lane = tid & 63, g = lane >> 4, col = lane & 15;
  const int chunk = blockIdx.x % NCHUNK, mt = blockIdx.x / NCHUNK;
  const int nbeg = chunk * CHUNK;
  const int nend = min(nbeg + CHUNK, NVOC);

  for (int i = tid; i < NTILE * 32; i += 256) {
    int n = nbeg + i;
    biasS[i] = (n < nend) ? (bm[n] - M0) * LOG2E : -1e30f;
  }

  const int arow0 = mt * 128 + wave * 32;
  long a0[24], a1[24];
  #pragma unroll
  for (int kk = 0; kk < 24; ++kk) {
    a0[kk] = *(const long*)(A8 + (size_t)(arow0 + col) * KDIM + kk * 32 + g * 8);
    a1[kk] = *(const long*)(A8 + (size_t)(arow0 + 16 + col) * KDIM + kk * 32 + g * 8);
  }

  float s[8];
  #pragma unroll
  for (int i = 0; i < 8; ++i) s[i] = 0.f;

  const int off0 = col * 8 + g * 256;
  const float kinv = INVSCALE * LOG2E;

  auto COMPUTE = [&](int t) {
    const char* B = &Bsm[t & 1][0] + off0;
    f32x4 acc00 = {0.f,0.f,0.f,0.f}, acc10 = {0.f,0.f,0.f,0.f};
    f32x4 acc01 = {0.f,0.f,0.f,0.f}, acc11 = {0.f,0.f,0.f,0.f};
    #pragma unroll
    for (int kk = 0; kk < 24; ++kk) {
      long b0 = *(const long*)(B + kk * 1024);
      long b1 = *(const long*)(B + kk * 1024 + 128);
      acc00 = __builtin_amdgcn_mfma_f32_16x16x32_fp8_fp8(a0[kk], b0, acc00, 0, 0, 0);
      acc10 = __builtin_amdgcn_mfma_f32_16x16x32_fp8_fp8(a1[kk], b0, acc10, 0, 0, 0);
      acc01 = __builtin_amdgcn_mfma_f32_16x16x32_fp8_fp8(a0[kk], b1, acc01, 0, 0, 0);
      acc11 = __builtin_amdgcn_mfma_f32_16x16x32_fp8_fp8(a1[kk], b1, acc11, 0, 0, 0);
    }
    const float b20 = biasS[t * 32 + col];
    const float b21 = biasS[t * 32 + 16 + col];
    #pragma unroll
    for (int rr = 0; rr < 4; ++rr) {
      s[rr]     += exp2f(fmaf(acc00[rr], kinv, b20)) + exp2f(fmaf(acc01[rr], kinv, b21));
      s[rr + 4] += exp2f(fmaf(acc10[rr], kinv, b20)) + exp2f(fmaf(acc11[rr], kinv, b21));
    }
  };

  if constexpr (WM8) {
    const char* cbase = Wm8 + (size_t)chunk * NTILE * TILEB;
    auto STAGE = [&](int buf, int tt) {
      const char* src = cbase + (size_t)tt * TILEB + wave * 1024 + lane * 16;
      char* dst = &Bsm[buf][0] + wave * 1024;
      #pragma unroll
      for (int j = 0; j < 6; ++j) {
        __builtin_amdgcn_global_load_lds((glds_g*)(src + j * 4096),
                                         (glds_l*)(dst + j * 4096), 16, 0, 0);
      }
    };
    STAGE(0, 0);
    asm volatile("s_waitcnt lgkmcnt(0)" ::: "memory");
    __builtin_amdgcn_s_barrier();
    for (int t = 0; t < NTILE; ++t) {
      int tn = (t + 1 < NTILE) ? t + 1 : 0;
      STAGE((t + 1) & 1, tn);
      asm volatile("s_waitcnt vmcnt(6)" ::: "memory");
      __builtin_amdgcn_s_barrier();
      __builtin_amdgcn_sched_barrier(0);
      __builtin_amdgcn_s_setprio(1);
      COMPUTE(t);
      __builtin_amdgcn_s_setprio(0);
      __builtin_amdgcn_sched_barrier(0);
      __builtin_amdgcn_s_barrier();
    }
  } else {
    __syncthreads();
    for (int t = 0; t < NTILE; ++t) {
      #pragma unroll
      for (int j = 0; j < 6; ++j) {
        int sg = j * 256 + tid;
        int kk = sg >> 6, gg = (sg >> 4) & 3, nl0 = (sg & 15) * 2;
        int n_a = nbeg + t * 32 + nl0, n_b = n_a + 1;
        int4 o = {0, 0, 0, 0};
        if (n_a < nend) {
          const float* wp = Wm + (size_t)n_a * KDIM + kk * 32 + gg * 8;
          o.x = pk4_fp8(((const float4*)wp)[0], WMSCALE);
          o.y = pk4_fp8(((const float4*)wp)[1], WMSCALE);
        }
        if (n_b < nend) {
          const float* wp = Wm + (size_t)n_b * KDIM + kk * 32 + gg * 8;
          o.z = pk4_fp8(((const float4*)wp)[0], WMSCALE);
          o.w = pk4_fp8(((const float4*)wp)[1], WMSCALE);
        }
        *(int4*)(&Bsm[0][0] + kk * 1024 + gg * 256 + nl0 * 8) = o;
      }
      __syncthreads();
      COMPUTE(t);
      __syncthreads();
    }
  }

  #pragma unroll
  for (int i = 0; i < 8; ++i) {
    float v = s[i];
    v += __shfl_xor(v, 1);
    v += __shfl_xor(v, 2);
    v += __shfl_xor(v, 4);
    v += __shfl_xor(v, 8);
    s[i] = v;
  }
  if (col == 0) {
    #pragma unroll
    for (int mblk = 0; mblk < 2; ++mblk)
      #pragma unroll
      for (int rr = 0; rr < 4; ++rr) {
        int tok = arow0 + mblk * 16 + g * 4 + rr;
        psum[tok * NCHUNK + chunk] = s[mblk * 4 + rr];
      }
  }
}

// ---------------- tail: tag (625 x 1-ntile, 24KB) | gold (1024) | embed (32) --
// Small-LDS kernel -> ~6 blocks/CU -> latency well hidden.
__global__ __launch_bounds__(256) void k_tail(
    const float* __restrict__ video, const float* __restrict__ title,
    const float* __restrict__ Wt, const float* __restrict__ bt,
    const float* __restrict__ ylab, const int* __restrict__ lab,
    const float* __restrict__ Wm, const float* __restrict__ bm,
    const float* __restrict__ Wh, const float* __restrict__ bh,
    float* __restrict__ out_sig, float* __restrict__ tagSum,
    float* __restrict__ gold, float* __restrict__ out_emb) {
  __shared__ __align__(64) char smem[24640];
  const int bid = blockIdx.x, tid = threadIdx.x;
  const int wave = tid >> 6, lane = tid & 63, g = lane >> 4, col = lane & 15;

  if (bid < TAG_BLKS) {
    // ---- tag head: 1 ntile (16 tags) x 32 batch rows ----
    unsigned short* Bt = (unsigned short*)smem;       // 24 KiB
    float* wsum = (float*)(smem + 24576);
    #pragma unroll
    for (int j = 0; j < 6; ++j) {
      int sg = j * 256 + tid;                // 0..1535
      int kk = sg >> 6, c = (sg & 63) >> 2, gg = sg & 3;
      int n = bid * 16 + c;
      bf16x8 o = {};
      if (n < NTAG) {
        const float* wp = Wt + (size_t)n * KDIM + kk * 32 + gg * 8;
        o = cvt8(((const float4*)wp)[0], ((const float4*)wp)[1]);
      }
      *(bf16x8*)((char*)Bt + sg * 16) = o;
    }
    __syncthreads();

    float lacc = 0.f;
    if (wave < 2) {
      const int mhalf = wave;
      bf16x8 a[24];
      const float* vrow = video + (size_t)(mhalf * 16 + col) * KDIM;
      #pragma unroll
      for (int kk = 0; kk < 24; ++kk) {
        a[kk] = cvt8(*(const float4*)(vrow + kk * 32 + g * 8),
                     *(const float4*)(vrow + kk * 32 + g * 8 + 4));
      }
      const char* Bb = (const char*)Bt + col * 64 + g * 16;
      f32x4 acc = {0.f, 0.f, 0.f, 0.f};
      #pragma unroll
      for (int kk = 0; kk < 24; ++kk) {
        bf16x8 b = *(const bf16x8*)(Bb + kk * 1024);
        acc = __builtin_amdgcn_mfma_f32_16x16x32_bf16(a[kk], b, acc, 0, 0, 0);
      }
      const int nc = bid * 16 + col;
      if (nc < NTAG) {
        const float bias = bt[nc];
        #pragma unroll
        for (int rr = 0; rr < 4; ++rr) {
          int brow = mhalf * 16 + g * 4 + rr;
          float x = acc[rr] + bias;
          out_sig[(size_t)brow * NTAG + nc] = 1.f / (1.f + __expf(-x));
          float y = ylab[(size_t)brow * NTAG + nc];
          lacc += fmaxf(x, 0.f) - x * y + log1pf(__expf(-fabsf(x)));
        }
      }
      #pragma unroll
      for (int m = 32; m; m >>= 1) lacc += __shfl_xor(lacc, m);
      if (lane == 0) wsum[wave] = lacc;
    }
    __syncthreads();
    if (tid == 0) atomicAdd(tagSum, wsum[0] + wsum[1]);

  } else if (bid < TAG_BLKS + GOLD_BLKS) {
    // ---- gold logit: 4 tokens per block (f32 exact) ----
    int tok = (bid - TAG_BLKS) * 4 + wave;
    int l = lab[tok];
    float acc = 0.f;
    #pragma unroll
    for (int j = 0; j < 12; ++j) {
      int k = j * 64 + lane;
      acc += title[(size_t)tok * KDIM + k] * Wm[(size_t)l * KDIM + k];
    }
    #pragma unroll
    for (int m = 32; m; m >>= 1) acc += __shfl_xor(acc, m);
    if (lane == 0) gold[tok] = acc + bm[l];

  } else {
    // ---- embedding head (f32 exact) ----
    float* feat = (float*)smem;                       // 6144 B
    float* red = (float*)(smem + 6144);
    const int b = bid - TAG_BLKS - GOLD_BLKS;
    #pragma unroll
    for (int j = 0; j < 6; ++j) {
      int k = j * 256 + tid;
      feat[k] = (k < KDIM) ? video[(size_t)b * KDIM + k]
                           : title[(size_t)b * 128 * KDIM + (k - KDIM)];
    }
    __syncthreads();
    float acc = bh[tid];
    #pragma unroll 8
    for (int k = 0; k < 1536; k += 4) {
      float4 w = *(const float4*)(Wh + (size_t)tid * 1536 + k);
      acc += w.x * feat[k] + w.y * feat[k + 1] + w.z * feat[k + 2] + w.w * feat[k + 3];
    }
    float ss = acc * acc;
    #pragma unroll
    for (int m = 32; m; m >>= 1) ss += __shfl_xor(ss, m);
    if (lane == 0) red[wave] = ss;
    __syncthreads();
    float nrm = sqrtf(red[0] + red[1] + red[2] + red[3]);
    float scale = 1.f / fmaxf(nrm, 1e-12f);
    out_emb[(size_t)b * HID + tid] = acc * scale;
  }
}

// ---------------- finalize losses ----------------
__global__ __launch_bounds__(256) void k_final(
    const float* __restrict__ psum, const float* __restrict__ gold,
    const int* __restrict__ lab, const float* __restrict__ tagSum,
    float* __restrict__ out) {
  __shared__ float red[4];
  const int tid = threadIdx.x, wave = tid >> 6, lane = tid & 63;
  if (tid == 0) out[OUT_LTAG] = tagSum[0] / 320000.f;

  float lm = 0.f;
  for (int tok = tid; tok < NTOK; tok += 256) {
    float S = 0.f;
    #pragma unroll
    for (int c = 0; c < NCHUNK; ++c) S += psum[tok * NCHUNK + c];
    float lse = M0 + logf(S);
    if (lab[tok] != 0) lm += lse - gold[tok];
  }
  #pragma unroll
  for (int m = 32; m; m >>= 1) lm += __shfl_xor(lm, m);
  if (lane == 0) red[wave] = lm;
  __syncthreads();
  if (tid == 0) out[OUT_LMLM] = red[0] + red[1] + red[2] + red[3];
}

extern "C" void kernel_launch(void* const* d_in, const int* in_sizes, int n_in,
                              void* d_out, int out_size, void* d_ws, size_t ws_size,
                              hipStream_t stream) {
  const float* video = (const float*)d_in[0];
  const float* title = (const float*)d_in[1];
  const float* ylab  = (const float*)d_in[2];
  const int*   lab   = (const int*)d_in[3];
  const float* Wt = (const float*)d_in[4];
  const float* bt = (const float*)d_in[5];
  const float* Wm = (const float*)d_in[6];
  const float* bm = (const float*)d_in[7];
  const float* Wh = (const float*)d_in[8];
  const float* bh = (const float*)d_in[9];
  float* out = (float*)d_out;
  char* ws = (char*)d_ws;

  char* wsA8   = ws + WS_A;
  float* wsPsum = (float*)(ws + WS_PSUM);
  float* wsGold = (float*)(ws + WS_GOLD);
  float* wsTagl = (float*)(ws + WS_TAGL);
  char* wsWm8  = ws + WS_WM8;

  const bool useWm8 = ws_size >= WS_NEED;

  hipMemsetAsync(wsTagl, 0, 4, stream);
  k_conv<<<CONV_BLKS + WMCV_BLKS, 256, 0, stream>>>(title, Wm, wsA8, wsWm8);
  if (useWm8)
    k_mlm<true><<<MLM_BLKS, 256, 0, stream>>>(wsA8, Wm, wsWm8, bm, wsPsum);
  else
    k_mlm<false><<<MLM_BLKS, 256, 0, stream>>>(wsA8, Wm, wsWm8, bm, wsPsum);
  k_tail<<<TAIL_GRID, 256, 0, stream>>>(
      video, title, Wt, bt, ylab, lab, Wm, bm, Wh, bh,
      out, wsTagl, wsGold, out + OUT_EMB);
  k_final<<<1, 256, 0, stream>>>(wsPsum, wsGold, lab, wsTagl, out);
}

// Round 18
// 161.345 us; speedup vs baseline: 1.2239x; 1.2239x over previous
//
#include <hip/hip_runtime.h>
#include <hip/hip_bf16.h>
#include <math.h>

typedef short bf16x8 __attribute__((ext_vector_type(8)));
typedef float f32x4 __attribute__((ext_vector_type(4)));

#define KDIM 768
#define NTAG 10000
#define NVOC 21128
#define HID 256
#define NTOK 4096
#define NCHUNK 24
#define CHUNK 881                 // ceil(21128/24)
#define NTILE 28                  // ceil(881/32)  (32-row tiles)
#define TILEB 24576               // bytes per packed B tile (32 rows x 768 fp8)
#define M0 4.0f                   // fixed softmax shift (logits ~N(0,0.55))
#define WMSCALE 16.0f             // Wm pre-scale (fp8 subnormal avoidance)
#define INVSCALE 0.0625f
#define LOG2E 1.44269504f

// ws layout (bytes)
#define WS_A     0ull                    // fp8  [4096][768] title          (3145728)
#define WS_AVID  3145728ull              // bf16 [32][768] video            (49152)
#define WS_PSUM  3194880ull              // f32  [4096][24]                 (393216)
#define WS_GOLD  3588096ull              // f32  [4096]                     (16384)
#define WS_TAGL  3604480ull              // f32  [1] atomic                 (64)
#define WS_WM8   3604544ull              // fp8 packed [24][28][24576]      (16515072)
#define WS_NEED  (WS_WM8 + 16515072ull + 65536ull)

#define OUT_EMB  320000
#define OUT_LTAG 328192
#define OUT_LMLM 328193

#define MLM_BLKS 768
#define TAG_BLKS 313
#define GOLD_BLKS 256             // 16 tokens per block
#define EMB_BLKS 32
#define CONV_BLKS 1548            // (393216+3072)/256 exactly
#define WMCV_BLKS (NCHUNK*NTILE)  // 672

typedef const __attribute__((address_space(1))) unsigned int glds_g;
typedef __attribute__((address_space(3))) unsigned int glds_l;

static __device__ __forceinline__ unsigned short f2bf(float f) {
  unsigned u = __builtin_bit_cast(unsigned, f);
  u = u + 0x7FFFu + ((u >> 16) & 1u);
  return (unsigned short)(u >> 16);
}

// pack 4 floats -> 4 fp8 e4m3 bytes
static __device__ __forceinline__ int pk4_fp8(float4 v, float scale) {
  int w = __builtin_amdgcn_cvt_pk_fp8_f32(v.x * scale, v.y * scale, 0, false);
  w = __builtin_amdgcn_cvt_pk_fp8_f32(v.z * scale, v.w * scale, w, true);
  return w;
}

static __device__ __forceinline__ bf16x8 cvt8(float4 f0, float4 f1) {
  bf16x8 o;
  o[0] = (short)f2bf(f0.x); o[1] = (short)f2bf(f0.y);
  o[2] = (short)f2bf(f0.z); o[3] = (short)f2bf(f0.w);
  o[4] = (short)f2bf(f1.x); o[5] = (short)f2bf(f1.y);
  o[6] = (short)f2bf(f1.z); o[7] = (short)f2bf(f1.w);
  return o;
}

// ---------------- fused conversions ----------------
// blocks [0,1548): title->fp8, video->bf16 (linear)
// blocks [1548,2220): Wm -> packed fp8 tile images (x16), LDS-transposed so
//   global reads AND writes stay coalesced.
// Packed tile image (32 rows x 768): piece (row r, k-octet q=kk*4+g) at byte
//   kk*1024 + g*256 + r*8.
__global__ __launch_bounds__(256) void k_conv(
    const float* __restrict__ title, const float* __restrict__ video,
    const float* __restrict__ Wm,
    char* __restrict__ A8, unsigned short* __restrict__ Avid,
    char* __restrict__ Wm8, float* __restrict__ tagSum) {
  __shared__ __align__(1024) char tsm[TILEB];
  const int bid = blockIdx.x, tid = threadIdx.x;
  if (bid < CONV_BLKS) {
    const int nT = 393216;
    int i = bid * 256 + tid;
    if (i == 0) tagSum[0] = 0.f;
    if (i < nT) {
      float4 v0 = ((const float4*)title)[i * 2];
      float4 v1 = ((const float4*)title)[i * 2 + 1];
      int2 o = {pk4_fp8(v0, 1.f), pk4_fp8(v1, 1.f)};
      *(int2*)(A8 + (size_t)i * 8) = o;
    } else {
      int j = i - nT;
      float4 v0 = ((const float4*)video)[j * 2];
      float4 v1 = ((const float4*)video)[j * 2 + 1];
      *(bf16x8*)(Avid + (size_t)j * 8) = cvt8(v0, v1);
    }
  } else {
    const int wblk = bid - CONV_BLKS;
    const int chunk = wblk / NTILE, tile = wblk % NTILE;
    const int n0 = chunk * CHUNK + tile * 32;
    const int nend = min(chunk * CHUNK + CHUNK, NVOC);
    // phase 1: coalesced read Wm rows, cvt, scatter to LDS packed image
    #pragma unroll
    for (int j = 0; j < 12; ++j) {
      int p = j * 256 + tid;            // 0..3071
      int r = p / 96, q = p % 96;       // row, k-octet
      int n = n0 + r;
      int2 o = {0, 0};
      if (n < nend) {
        const float* wp = Wm + (size_t)n * KDIM + q * 8;
        o.x = pk4_fp8(((const float4*)wp)[0], WMSCALE);
        o.y = pk4_fp8(((const float4*)wp)[1], WMSCALE);
      }
      *(int2*)(tsm + (q >> 2) * 1024 + (q & 3) * 256 + r * 8) = o;
    }
    __syncthreads();
    // phase 2: coalesced 16B writes of the image
    char* dst = Wm8 + (size_t)wblk * TILEB;
    #pragma unroll
    for (int j = 0; j < 6; ++j) {
      int idx = j * 256 + tid;
      *(int4*)(dst + idx * 16) = *(const int4*)(tsm + idx * 16);
    }
  }
}

// ---------------- fused main: MLM GEMM (0..767) | tag | gold | embed ----------------
// MLM: chunk = bid%24 (XCD c%8), mt = bid/24. 4 waves x 32 rows x 32-col tiles.
// LDS B tile 24KB packed image; lane (g,col) b64-reads at col*8+g*256+kk*1024
// (+128 second N-half) -> conflict-free. 2-buffer, vmcnt(6), 2 barriers/tile.
template<bool WM8>
__global__ __launch_bounds__(256)
__attribute__((amdgpu_waves_per_eu(3, 3)))
void k_main(
    const char* __restrict__ A8,
    const float* __restrict__ Wm,
    const char* __restrict__ Wm8,
    const float* __restrict__ bm,
    float* __restrict__ psum,
    const unsigned short* __restrict__ Avid,
    const float* __restrict__ Wt, const float* __restrict__ bt,
    const float* __restrict__ ylab,
    const float* __restrict__ title, const int* __restrict__ lab,
    const float* __restrict__ video,
    const float* __restrict__ Wh, const float* __restrict__ bh,
    float* __restrict__ out_sig, float* __restrict__ tagSum,
    float* __restrict__ gold, float* __restrict__ out_emb) {
  __shared__ __align__(1024) char smem[2 * TILEB + 3584];   // 52736 B
  const int bid = blockIdx.x, tid = threadIdx.x;
  const int wave = tid >> 6, lane = tid & 63, g = lane >> 4, col16 = lane & 15;

  if (bid < MLM_BLKS) {
    char (*Bsm)[TILEB] = (char(*)[TILEB])smem;
    float* biasS = (float*)(smem + 2 * TILEB);              // [NTILE*32]
    const int chunk = bid % NCHUNK, mt = bid / NCHUNK;
    const int nbeg = chunk * CHUNK;
    const int nend = min(nbeg + CHUNK, NVOC);
    const int col = col16;

    for (int i = tid; i < NTILE * 32; i += 256) {
      int n = nbeg + i;
      biasS[i] = (n < nend) ? (bm[n] - M0) * LOG2E : -1e30f;
    }

    const int arow0 = mt * 128 + wave * 32;
    long a0[24], a1[24];
    #pragma unroll
    for (int kk = 0; kk < 24; ++kk) {
      a0[kk] = *(const long*)(A8 + (size_t)(arow0 + col) * KDIM + kk * 32 + g * 8);
      a1[kk] = *(const long*)(A8 + (size_t)(arow0 + 16 + col) * KDIM + kk * 32 + g * 8);
    }

    float s[8];
    #pragma unroll
    for (int i = 0; i < 8; ++i) s[i] = 0.f;

    const int off0 = col * 8 + g * 256;
    const float kinv = INVSCALE * LOG2E;

    auto COMPUTE = [&](int t) {
      const char* B = &Bsm[t & 1][0] + off0;
      f32x4 acc00 = {0.f,0.f,0.f,0.f}, acc10 = {0.f,0.f,0.f,0.f};
      f32x4 acc01 = {0.f,0.f,0.f,0.f}, acc11 = {0.f,0.f,0.f,0.f};
      #pragma unroll
      for (int kk = 0; kk < 24; ++kk) {
        long b0 = *(const long*)(B + kk * 1024);
        long b1 = *(const long*)(B + kk * 1024 + 128);
        acc00 = __builtin_amdgcn_mfma_f32_16x16x32_fp8_fp8(a0[kk], b0, acc00, 0, 0, 0);
        acc10 = __builtin_amdgcn_mfma_f32_16x16x32_fp8_fp8(a1[kk], b0, acc10, 0, 0, 0);
        acc01 = __builtin_amdgcn_mfma_f32_16x16x32_fp8_fp8(a0[kk], b1, acc01, 0, 0, 0);
        acc11 = __builtin_amdgcn_mfma_f32_16x16x32_fp8_fp8(a1[kk], b1, acc11, 0, 0, 0);
      }
      const float b20 = biasS[t * 32 + col];
      const float b21 = biasS[t * 32 + 16 + col];
      #pragma unroll
      for (int rr = 0; rr < 4; ++rr) {
        s[rr]     += exp2f(fmaf(acc00[rr], kinv, b20)) + exp2f(fmaf(acc01[rr], kinv, b21));
        s[rr + 4] += exp2f(fmaf(acc10[rr], kinv, b20)) + exp2f(fmaf(acc11[rr], kinv, b21));
      }
    };

    if constexpr (WM8) {
      const char* cbase = Wm8 + (size_t)chunk * NTILE * TILEB;
      auto STAGE = [&](int buf, int tt) {
        const char* src = cbase + (size_t)tt * TILEB + wave * 1024 + lane * 16;
        char* dst = &Bsm[buf][0] + wave * 1024;
        #pragma unroll
        for (int j = 0; j < 6; ++j) {
          __builtin_amdgcn_global_load_lds((glds_g*)(src + j * 4096),
                                           (glds_l*)(dst + j * 4096), 16, 0, 0);
        }
      };
      STAGE(0, 0);
      asm volatile("s_waitcnt lgkmcnt(0)" ::: "memory");
      __builtin_amdgcn_s_barrier();
      for (int t = 0; t < NTILE; ++t) {
        int tn = (t + 1 < NTILE) ? t + 1 : 0;
        STAGE((t + 1) & 1, tn);
        asm volatile("s_waitcnt vmcnt(6)" ::: "memory");
        __builtin_amdgcn_s_barrier();
        __builtin_amdgcn_sched_barrier(0);
        __builtin_amdgcn_s_setprio(1);
        COMPUTE(t);
        __builtin_amdgcn_s_setprio(0);
        __builtin_amdgcn_sched_barrier(0);
        __builtin_amdgcn_s_barrier();
      }
    } else {
      __syncthreads();
      for (int t = 0; t < NTILE; ++t) {
        #pragma unroll
        for (int j = 0; j < 6; ++j) {
          int sg = j * 256 + tid;
          int kk = sg >> 6, gg = (sg >> 4) & 3, nl0 = (sg & 15) * 2;
          int n_a = nbeg + t * 32 + nl0, n_b = n_a + 1;
          int4 o = {0, 0, 0, 0};
          if (n_a < nend) {
            const float* wp = Wm + (size_t)n_a * KDIM + kk * 32 + gg * 8;
            o.x = pk4_fp8(((const float4*)wp)[0], WMSCALE);
            o.y = pk4_fp8(((const float4*)wp)[1], WMSCALE);
          }
          if (n_b < nend) {
            const float* wp = Wm + (size_t)n_b * KDIM + kk * 32 + gg * 8;
            o.z = pk4_fp8(((const float4*)wp)[0], WMSCALE);
            o.w = pk4_fp8(((const float4*)wp)[1], WMSCALE);
          }
          *(int4*)(&Bsm[0][0] + kk * 1024 + gg * 256 + nl0 * 8) = o;
        }
        __syncthreads();
        COMPUTE(t);
        __syncthreads();
      }
    }

    #pragma unroll
    for (int i = 0; i < 8; ++i) {
      float v = s[i];
      v += __shfl_xor(v, 1);
      v += __shfl_xor(v, 2);
      v += __shfl_xor(v, 4);
      v += __shfl_xor(v, 8);
      s[i] = v;
    }
    if (col == 0) {
      #pragma unroll
      for (int mblk = 0; mblk < 2; ++mblk)
        #pragma unroll
        for (int rr = 0; rr < 4; ++rr) {
          int tok = arow0 + mblk * 16 + g * 4 + rr;
          psum[tok * NCHUNK + chunk] = s[mblk * 4 + rr];
        }
    }

  } else if (bid < MLM_BLKS + TAG_BLKS) {
    // ---- tag head: 2 ntiles/block, Wt staged coalesced -> bf16 LDS ----
    const int tb = bid - MLM_BLKS;
    unsigned short* Bt = (unsigned short*)smem;       // 48 KiB
    float* wsum = (float*)(smem + 49152);
    #pragma unroll
    for (int j = 0; j < 12; ++j) {
      int sg = j * 256 + tid;
      int tt = (j >= 6) ? 1 : 0;
      int sgl = sg - tt * 1536;
      int kk = sgl >> 6, c = (sgl & 63) >> 2, gg = sgl & 3;
      int n = (tb * 2 + tt) * 16 + c;
      bf16x8 o = {};
      if (n < NTAG) {
        const float* wp = Wt + (size_t)n * KDIM + kk * 32 + gg * 8;
        o = cvt8(((const float4*)wp)[0], ((const float4*)wp)[1]);
      }
      *(bf16x8*)((char*)Bt + sg * 16) = o;
    }
    __syncthreads();

    const int ntile = tb * 2 + (wave >> 1), mhalf = wave & 1;
    float lacc = 0.f;
    if (ntile < 625) {
      bf16x8 a[24];
      #pragma unroll
      for (int kk = 0; kk < 24; ++kk)
        a[kk] = *(const bf16x8*)(Avid + (size_t)(mhalf * 16 + col16) * KDIM + kk * 32 + g * 8);
      const char* Bb = (const char*)Bt + (wave >> 1) * 24576 + col16 * 64 + g * 16;
      f32x4 acc = {0.f, 0.f, 0.f, 0.f};
      #pragma unroll
      for (int kk = 0; kk < 24; ++kk) {
        bf16x8 b = *(const bf16x8*)(Bb + kk * 1024);
        acc = __builtin_amdgcn_mfma_f32_16x16x32_bf16(a[kk], b, acc, 0, 0, 0);
      }
      const int nc = ntile * 16 + col16;
      if (nc < NTAG) {
        const float bias = bt[nc];
        #pragma unroll
        for (int rr = 0; rr < 4; ++rr) {
          int brow = mhalf * 16 + g * 4 + rr;
          float x = acc[rr] + bias;
          out_sig[(size_t)brow * NTAG + nc] = 1.f / (1.f + __expf(-x));
          float y = ylab[(size_t)brow * NTAG + nc];
          lacc += fmaxf(x, 0.f) - x * y + log1pf(__expf(-fabsf(x)));
        }
      }
    }
    #pragma unroll
    for (int m = 32; m; m >>= 1) lacc += __shfl_xor(lacc, m);
    if (lane == 0) wsum[wave] = lacc;
    __syncthreads();
    if (tid == 0) atomicAdd(tagSum, wsum[0] + wsum[1] + wsum[2] + wsum[3]);

  } else if (bid < MLM_BLKS + TAG_BLKS + GOLD_BLKS) {
    // ---- gold logits: 16 tokens per block (f32 exact) ----
    const int tbase = (bid - MLM_BLKS - TAG_BLKS) * 16;
    #pragma unroll
    for (int u = 0; u < 4; ++u) {
      int tok = tbase + wave * 4 + u;
      int l = lab[tok];
      float acc = 0.f;
      #pragma unroll
      for (int j = 0; j < 12; ++j) {
        int k = j * 64 + lane;
        acc += title[(size_t)tok * KDIM + k] * Wm[(size_t)l * KDIM + k];
      }
      #pragma unroll
      for (int m = 32; m; m >>= 1) acc += __shfl_xor(acc, m);
      if (lane == 0) gold[tok] = acc + bm[l];
    }

  } else {
    // ---- embedding head (f32 exact) ----
    float* feat = (float*)smem;
    float* red = (float*)(smem + 49152);
    const int b = bid - MLM_BLKS - TAG_BLKS - GOLD_BLKS;
    #pragma unroll
    for (int j = 0; j < 6; ++j) {
      int k = j * 256 + tid;
      feat[k] = (k < KDIM) ? video[(size_t)b * KDIM + k]
                           : title[(size_t)b * 128 * KDIM + (k - KDIM)];
    }
    __syncthreads();
    float acc = bh[tid];
    #pragma unroll 8
    for (int k = 0; k < 1536; k += 4) {
      float4 w = *(const float4*)(Wh + (size_t)tid * 1536 + k);
      acc += w.x * feat[k] + w.y * feat[k + 1] + w.z * feat[k + 2] + w.w * feat[k + 3];
    }
    float ss = acc * acc;
    #pragma unroll
    for (int m = 32; m; m >>= 1) ss += __shfl_xor(ss, m);
    if (lane == 0) red[wave] = ss;
    __syncthreads();
    float nrm = sqrtf(red[0] + red[1] + red[2] + red[3]);
    float scale = 1.f / fmaxf(nrm, 1e-12f);
    out_emb[(size_t)b * HID + tid] = acc * scale;
  }
}

// ---------------- finalize losses ----------------
__global__ __launch_bounds__(256) void k_final(
    const float* __restrict__ psum, const float* __restrict__ gold,
    const int* __restrict__ lab, const float* __restrict__ tagSum,
    float* __restrict__ out) {
  __shared__ float red[4];
  const int tid = threadIdx.x, wave = tid >> 6, lane = tid & 63;
  if (tid == 0) out[OUT_LTAG] = tagSum[0] / 320000.f;

  float lm = 0.f;
  for (int tok = tid; tok < NTOK; tok += 256) {
    float S = 0.f;
    #pragma unroll
    for (int c = 0; c < NCHUNK; ++c) S += psum[tok * NCHUNK + c];
    float lse = M0 + logf(S);
    if (lab[tok] != 0) lm += lse - gold[tok];
  }
  #pragma unroll
  for (int m = 32; m; m >>= 1) lm += __shfl_xor(lm, m);
  if (lane == 0) red[wave] = lm;
  __syncthreads();
  if (tid == 0) out[OUT_LMLM] = red[0] + red[1] + red[2] + red[3];
}

extern "C" void kernel_launch(void* const* d_in, const int* in_sizes, int n_in,
                              void* d_out, int out_size, void* d_ws, size_t ws_size,
                              hipStream_t stream) {
  const float* video = (const float*)d_in[0];
  const float* title = (const float*)d_in[1];
  const float* ylab  = (const float*)d_in[2];
  const int*   lab   = (const int*)d_in[3];
  const float* Wt = (const float*)d_in[4];
  const float* bt = (const float*)d_in[5];
  const float* Wm = (const float*)d_in[6];
  const float* bm = (const float*)d_in[7];
  const float* Wh = (const float*)d_in[8];
  const float* bh = (const float*)d_in[9];
  float* out = (float*)d_out;
  char* ws = (char*)d_ws;

  char* wsA8   = ws + WS_A;
  unsigned short* wsAvid = (unsigned short*)(ws + WS_AVID);
  float* wsPsum = (float*)(ws + WS_PSUM);
  float* wsGold = (float*)(ws + WS_GOLD);
  float* wsTagl = (float*)(ws + WS_TAGL);
  char* wsWm8  = ws + WS_WM8;

  const bool useWm8 = ws_size >= WS_NEED;
  const int mainGrid = MLM_BLKS + TAG_BLKS + GOLD_BLKS + EMB_BLKS;

  k_conv<<<CONV_BLKS + WMCV_BLKS, 256, 0, stream>>>(
      title, video, Wm, wsA8, wsAvid, wsWm8, wsTagl);
  if (useWm8)
    k_main<true><<<mainGrid, 256, 0, stream>>>(
        wsA8, Wm, wsWm8, bm, wsPsum, wsAvid, Wt, bt, ylab, title, lab,
        video, Wh, bh, out, wsTagl, wsGold, out + OUT_EMB);
  else
    k_main<false><<<mainGrid, 256, 0, stream>>>(
        wsA8, Wm, wsWm8, bm, wsPsum, wsAvid, Wt, bt, ylab, title, lab,
        video, Wh, bh, out, wsTagl, wsGold, out + OUT_EMB);
  k_final<<<1, 256, 0, stream>>>(wsPsum, wsGold, lab, wsTagl, out);
}